// Round 1
// baseline (61.237 us; speedup 1.0000x reference)
//
#include <hip/hip_runtime.h>
#include <math.h>

// Problem constants (from reference setup_inputs)
#define NB      32      // batch
#define NKV     8       // kv heads
#define NQ      32      // query heads
#define GQ      4       // GQA group size = NQ/NKV
#define DH      128     // head dim
#define TPP     16      // tokens per page
#define PPS     128     // pages per slot
#define NPAGES  4096    // total pages
#define NSPLIT  8       // S-splits per (b,kv)
#define PAGE_F  (TPP*DH)        // floats per page = 2048
#define PART_F  (GQ*DH + 2*GQ)  // partial size: o[4][128] + m[4] + l[4] = 520

// ---------------------------------------------------------------------------
// Kernel 1: per-(b, kv, split) flash-style partial attention over an
// interleaved subset of pages (p = split, split+8, split+16, ...).
// Writes unnormalized o, running max m, running sum l to workspace.
// ---------------------------------------------------------------------------
__global__ __launch_bounds__(256) void pa_partial(
    const float* __restrict__ query,
    const float* __restrict__ key_pages,
    const float* __restrict__ value_pages,
    const int*   __restrict__ page_map,
    const int*   __restrict__ seq_lengths,
    float*       __restrict__ ws)
{
    const int blk = blockIdx.x;          // ((b*NKV)+kv)*NSPLIT + sp
    const int sp  = blk & (NSPLIT - 1);
    const int kv  = (blk >> 3) & (NKV - 1);
    const int b   = blk >> 6;
    const int tid = threadIdx.x;

    const int seq     = seq_lengths[b];
    const int n_pages = (seq + TPP - 1) / TPP;
    if (sp >= n_pages) return;           // no pages for this split; combine skips it

    __shared__ __align__(16) float kbuf[TPP * DH];   // 8 KB
    __shared__ __align__(16) float vbuf[TPP * DH];   // 8 KB
    __shared__ float s_sc[GQ][TPP];                  // scores for current page

    // score-phase mapping: wave wv handles tokens 4*wv..4*wv+3; within a wave,
    // groups of 16 lanes share one token, each lane covers 8 d-elements.
    const int lane = tid & 63;
    const int wv   = tid >> 6;
    const int tok  = wv * 4 + (lane >> 4);
    const int l16  = lane & 15;
    const int d0   = l16 * 8;

    // PV/output mapping: thread covers (gA, d) and (gB, d)
    const int d  = tid & 127;
    const int gA = tid >> 7;     // 0 or 1
    const int gB = gA + 2;       // 2 or 3

    // Q fragments for the score phase (per-lane d-slice, all 4 group heads)
    float qreg[GQ][8];
    #pragma unroll
    for (int g = 0; g < GQ; ++g) {
        const float4* qp = (const float4*)(query + (size_t)((b * NQ + kv * GQ + g) * DH + d0));
        const float4 a = qp[0], c = qp[1];
        qreg[g][0] = a.x; qreg[g][1] = a.y; qreg[g][2] = a.z; qreg[g][3] = a.w;
        qreg[g][4] = c.x; qreg[g][5] = c.y; qreg[g][6] = c.z; qreg[g][7] = c.w;
    }

    float mA = -INFINITY, mB = -INFINITY;
    float lA = 0.f, lB = 0.f;
    float accA = 0.f, accB = 0.f;

    for (int p = sp; p < n_pages; p += NSPLIT) {
        const int pg = page_map[b * PPS + p];
        const float4* kg = (const float4*)(key_pages   + (size_t)(kv * NPAGES + pg) * PAGE_F);
        const float4* vg = (const float4*)(value_pages + (size_t)(kv * NPAGES + pg) * PAGE_F);

        __syncthreads();   // protect LDS from previous iteration's readers
        {
            float4* kb = (float4*)kbuf;
            float4* vb = (float4*)vbuf;
            kb[tid]       = kg[tid];
            kb[tid + 256] = kg[tid + 256];
            vb[tid]       = vg[tid];
            vb[tid + 256] = vg[tid + 256];
        }
        __syncthreads();

        // ---- scores: s[g][tok] = q[g] . k[tok] ----
        float part0, part1, part2, part3;
        {
            const float4 k0 = *(const float4*)&kbuf[tok * DH + d0];
            const float4 k1 = *(const float4*)&kbuf[tok * DH + d0 + 4];
            part0 = qreg[0][0]*k0.x + qreg[0][1]*k0.y + qreg[0][2]*k0.z + qreg[0][3]*k0.w
                  + qreg[0][4]*k1.x + qreg[0][5]*k1.y + qreg[0][6]*k1.z + qreg[0][7]*k1.w;
            part1 = qreg[1][0]*k0.x + qreg[1][1]*k0.y + qreg[1][2]*k0.z + qreg[1][3]*k0.w
                  + qreg[1][4]*k1.x + qreg[1][5]*k1.y + qreg[1][6]*k1.z + qreg[1][7]*k1.w;
            part2 = qreg[2][0]*k0.x + qreg[2][1]*k0.y + qreg[2][2]*k0.z + qreg[2][3]*k0.w
                  + qreg[2][4]*k1.x + qreg[2][5]*k1.y + qreg[2][6]*k1.z + qreg[2][7]*k1.w;
            part3 = qreg[3][0]*k0.x + qreg[3][1]*k0.y + qreg[3][2]*k0.z + qreg[3][3]*k0.w
                  + qreg[3][4]*k1.x + qreg[3][5]*k1.y + qreg[3][6]*k1.z + qreg[3][7]*k1.w;
            #pragma unroll
            for (int off = 8; off >= 1; off >>= 1) {
                part0 += __shfl_xor(part0, off);
                part1 += __shfl_xor(part1, off);
                part2 += __shfl_xor(part2, off);
                part3 += __shfl_xor(part3, off);
            }
        }
        const int tglob = p * TPP + tok;
        if (l16 < GQ) {
            const float val = (l16 == 0) ? part0 : (l16 == 1) ? part1
                            : (l16 == 2) ? part2 : part3;
            s_sc[l16][tok] = (tglob < seq) ? val : -1e30f;   // masked -> weight 0
        }
        __syncthreads();

        // ---- online softmax update (each thread tracks heads gA, gB) ----
        float sA[TPP], sB[TPP];
        #pragma unroll
        for (int t = 0; t < TPP; ++t) { sA[t] = s_sc[gA][t]; sB[t] = s_sc[gB][t]; }

        float pA = -1e30f, pB = -1e30f;
        #pragma unroll
        for (int t = 0; t < TPP; ++t) { pA = fmaxf(pA, sA[t]); pB = fmaxf(pB, sB[t]); }

        const float mnA = fmaxf(mA, pA), mnB = fmaxf(mB, pB);
        const float scA = __expf(mA - mnA), scB = __expf(mB - mnB);
        mA = mnA; mB = mnB;

        float sumA = 0.f, sumB = 0.f;
        #pragma unroll
        for (int t = 0; t < TPP; ++t) {
            sA[t] = __expf(sA[t] - mnA); sumA += sA[t];
            sB[t] = __expf(sB[t] - mnB); sumB += sB[t];
        }
        lA = lA * scA + sumA;
        lB = lB * scB + sumB;
        accA *= scA;
        accB *= scB;

        // ---- PV accumulate: lanes read consecutive d -> conflict-free ----
        #pragma unroll
        for (int t = 0; t < TPP; ++t) {
            const float v = vbuf[t * DH + d];
            accA += sA[t] * v;
            accB += sB[t] * v;
        }
    }

    // ---- write partial (o unnormalized, m, l) ----
    float* base = ws + (size_t)blk * PART_F;
    base[gA * DH + d] = accA;
    base[gB * DH + d] = accB;
    if (d == 0) {  // tid 0 writes g0,g2 ; tid 128 writes g1,g3
        base[GQ * DH + gA]      = mA;
        base[GQ * DH + GQ + gA] = lA;
        base[GQ * DH + gB]      = mB;
        base[GQ * DH + GQ + gB] = lB;
    }
}

// ---------------------------------------------------------------------------
// Kernel 2: combine the <=8 split partials per (b, kv) and write the output.
// ---------------------------------------------------------------------------
__global__ __launch_bounds__(256) void pa_combine(
    const float* __restrict__ ws,
    const int*   __restrict__ seq_lengths,
    float*       __restrict__ out)
{
    const int blk = blockIdx.x;    // b*NKV + kv
    const int b   = blk >> 3;
    const int kv  = blk & 7;
    const int tid = threadIdx.x;
    const int d   = tid & 127;
    const int gA  = tid >> 7;
    const int gB  = gA + 2;

    const int seq     = seq_lengths[b];
    const int n_pages = (seq + TPP - 1) / TPP;
    const int ns      = (n_pages < NSPLIT) ? n_pages : NSPLIT;

    const float* base0 = ws + (size_t)blk * NSPLIT * PART_F;

    float MA = -INFINITY, MB = -INFINITY;
    for (int si = 0; si < ns; ++si) {
        const float* p = base0 + si * PART_F;
        MA = fmaxf(MA, p[GQ * DH + gA]);
        MB = fmaxf(MB, p[GQ * DH + gB]);
    }

    float LA = 0.f, LB = 0.f, oA = 0.f, oB = 0.f;
    for (int si = 0; si < ns; ++si) {
        const float* p = base0 + si * PART_F;
        const float eA = __expf(p[GQ * DH + gA] - MA);
        const float eB = __expf(p[GQ * DH + gB] - MB);
        LA += p[GQ * DH + GQ + gA] * eA;
        LB += p[GQ * DH + GQ + gB] * eB;
        oA += p[gA * DH + d] * eA;
        oB += p[gB * DH + d] * eB;
    }

    float* ob = out + (size_t)(b * NQ + kv * GQ) * DH;
    ob[gA * DH + d] = oA / LA;
    ob[gB * DH + d] = oB / LB;
}

// ---------------------------------------------------------------------------
extern "C" void kernel_launch(void* const* d_in, const int* in_sizes, int n_in,
                              void* d_out, int out_size, void* d_ws, size_t ws_size,
                              hipStream_t stream)
{
    const float* query       = (const float*)d_in[0];
    const float* key_pages   = (const float*)d_in[1];
    const float* value_pages = (const float*)d_in[2];
    const int*   page_map    = (const int*)d_in[3];
    const int*   seq_lengths = (const int*)d_in[4];
    float*       out         = (float*)d_out;
    float*       ws          = (float*)d_ws;

    // ws usage: NB*NKV*NSPLIT * PART_F floats = 2048 * 520 * 4B ~= 4.26 MB
    pa_partial<<<NB * NKV * NSPLIT, 256, 0, stream>>>(
        query, key_pages, value_pages, page_map, seq_lengths, ws);
    pa_combine<<<NB * NKV, 256, 0, stream>>>(ws, seq_lengths, out);
}